// Round 3
// baseline (636.041 us; speedup 1.0000x reference)
//
#include <hip/hip_runtime.h>

// ---------------- problem constants ----------------
#define BB   16
#define NN   512
#define DD   1024
#define NHH  16
#define DKK  64
#define DFF  4096
#define MM   (BB*NN)     // 8192 rows

typedef _Float16 h16;
typedef h16  h16x8 __attribute__((ext_vector_type(8)));
typedef h16  h16x4 __attribute__((ext_vector_type(4)));
typedef float f32x4 __attribute__((ext_vector_type(4)));

#define AS1 __attribute__((address_space(1)))
#define AS3 __attribute__((address_space(3)))

__device__ __forceinline__ void gld16(h16* lds_dst, const h16* g_src) {
  // async global->LDS, 16B per lane; LDS dest must be lane-linear (it is: c*16B)
  __builtin_amdgcn_global_load_lds((const AS1 void*)g_src, (AS3 void*)lds_dst, 16, 0, 0);
}

// ---------------- LayerNorm row kernel: fp32 [rows][1024] -> f16 ----------------
__global__ __launch_bounds__(256) void ln_k(const float* __restrict__ in, h16* __restrict__ out)
{
  const int row = blockIdx.x;
  const int tid = threadIdx.x;
  const float4 v = ((const float4*)(in + (long)row * DD))[tid];
  float s  = v.x + v.y + v.z + v.w;
  float ss = v.x*v.x + v.y*v.y + v.z*v.z + v.w*v.w;
#pragma unroll
  for (int d = 32; d > 0; d >>= 1) { s += __shfl_down(s, d); ss += __shfl_down(ss, d); }
  __shared__ float red[8];
  const int wv = tid >> 6, ln = tid & 63;
  if (ln == 0) { red[wv] = s; red[4 + wv] = ss; }
  __syncthreads();
  s  = red[0] + red[1] + red[2] + red[3];
  ss = red[4] + red[5] + red[6] + red[7];
  const float mean = s * (1.0f / DD);
  const float var  = ss * (1.0f / DD) - mean * mean;
  const float rstd = rsqrtf(var + 1e-5f);
  h16x4 o;
  o[0] = (h16)((v.x - mean) * rstd);
  o[1] = (h16)((v.y - mean) * rstd);
  o[2] = (h16)((v.z - mean) * rstd);
  o[3] = (h16)((v.w - mean) * rstd);
  ((h16x4*)(out + (long)row * DD))[tid] = o;
}

// ---------------- transpose-cast: src fp32 [R][C] -> dst f16 [C][R], batched ----------------
__global__ __launch_bounds__(256) void tcast_k(const float* __restrict__ src, h16* __restrict__ dst,
                                               int R, int C, long sB, long dB)
{
  __shared__ float tile[32][33];
  const float* s = src + (long)blockIdx.z * sB;
  h16* d = dst + (long)blockIdx.z * dB;
  const int c0 = blockIdx.x * 32, r0 = blockIdx.y * 32;
  const int tx = threadIdx.x & 31, ty = threadIdx.x >> 5;   // 32 x 8
#pragma unroll
  for (int i = 0; i < 32; i += 8)
    tile[ty + i][tx] = s[(long)(r0 + ty + i) * C + c0 + tx];
  __syncthreads();
#pragma unroll
  for (int i = 0; i < 32; i += 8)
    d[(long)(c0 + ty + i) * R + r0 + tx] = (h16)tile[tx][ty + i];
}

// ---------------- f16 MFMA GEMM: C[M][Nc] = A[M][K] * Bt[Nc][K]^T, epilogue variants ----------------
// EPI 0: QKV scatter (+bias)  EPI 1: x = C + bo + H  EPI 2: hff = relu(C+b1)  EPI 3: out = C + b2 + x
template<int EPI>
__global__ __launch_bounds__(256) void gemm_k(
    const h16* __restrict__ A, const h16* __restrict__ Bt, int K, int Nc,
    const float* __restrict__ bias0, const float* __restrict__ bias1, const float* __restrict__ bias2,
    h16* __restrict__ o0, h16* __restrict__ o1, h16* __restrict__ o2,
    float* __restrict__ of, const float* __restrict__ addsrc)
{
  __shared__ h16 Asb[128 * 32];
  __shared__ h16 Bsb[128 * 32];
  const int tid  = threadIdx.x;
  const int wave = tid >> 6, lane = tid & 63;
  const int lr = lane & 15, lq = lane >> 4;
  const int m0 = blockIdx.y * 128, n0 = blockIdx.x * 128;
  const int wr = (wave >> 1) * 64, wc = (wave & 1) * 64;

  const int c0 = tid,        ar0 = c0 >> 2, as0 = (c0 & 3) * 8;
  const int c1 = 256 + tid,  ar1 = c1 >> 2, as1 = (c1 & 3) * 8;

  f32x4 acc[4][4] = {};

  for (int k0 = 0; k0 < K; k0 += 32) {
    gld16(Asb + c0 * 8, A  + (long)(m0 + ar0) * K + k0 + as0);
    gld16(Asb + c1 * 8, A  + (long)(m0 + ar1) * K + k0 + as1);
    gld16(Bsb + c0 * 8, Bt + (long)(n0 + ar0) * K + k0 + as0);
    gld16(Bsb + c1 * 8, Bt + (long)(n0 + ar1) * K + k0 + as1);
    __syncthreads();
    h16x8 af[4], bf[4];
#pragma unroll
    for (int i = 0; i < 4; ++i) {
      af[i] = *(const h16x8*)(Asb + (wr + i * 16 + lr) * 32 + lq * 8);
      bf[i] = *(const h16x8*)(Bsb + (wc + i * 16 + lr) * 32 + lq * 8);
    }
#pragma unroll
    for (int i = 0; i < 4; ++i)
#pragma unroll
      for (int j = 0; j < 4; ++j)
        acc[i][j] = __builtin_amdgcn_mfma_f32_16x16x32_f16(af[i], bf[j], acc[i][j], 0, 0, 0);
    __syncthreads();
  }

  // epilogue: C/D layout row = (lane>>4)*4 + reg, col = lane&15
#pragma unroll
  for (int i = 0; i < 4; ++i) {
#pragma unroll
    for (int jn = 0; jn < 4; ++jn) {
#pragma unroll
      for (int j = 0; j < 4; ++j) {
        const int m   = m0 + wr + i * 16 + lq * 4 + j;
        const int col = n0 + wc + jn * 16 + lr;
        float v = acc[i][jn][j];
        if constexpr (EPI == 0) {
          const int w  = col >> 10;            // 0=Q 1=K 2=V (block-uniform)
          const int hh = (col >> 6) & 15, kk = col & 63;
          const int bidx = m >> 9, nq = m & 511;
          const int bcol = col & 1023;
          if (w == 0)      o0[(((long)bidx * NHH + hh) * NN + nq) * DKK + kk] = (h16)(v + bias0[bcol]);
          else if (w == 1) o1[(((long)bidx * NHH + hh) * NN + nq) * DKK + kk] = (h16)(v + bias1[bcol]);
          else             o2[(((long)bidx * NHH + hh) * DKK + kk) * NN + nq] = (h16)(v + bias2[bcol]);
        } else if constexpr (EPI == 1) {
          of[(long)m * Nc + col] = v + bias0[col] + addsrc[(long)m * Nc + col];
        } else if constexpr (EPI == 2) {
          o0[(long)m * Nc + col] = (h16)fmaxf(v + bias0[col], 0.0f);
        } else {
          of[(long)m * Nc + col] = v + bias0[col] + addsrc[(long)m * Nc + col];
        }
      }
    }
  }
}

// ---------------- flash attention: per (b,h), 128 q-rows/block, 64-key chunks ----------------
__global__ __launch_bounds__(256) void attn_k(
    const h16* __restrict__ Qh, const h16* __restrict__ Kh, const h16* __restrict__ Vt,
    const float* __restrict__ spm, h16* __restrict__ Oh)
{
  __shared__ h16 Qs[128 * 64];      // 16 KB
  __shared__ h16 Ks[64 * 64];       //  8 KB  [key][dk]
  __shared__ h16 Vts[64 * 64];      //  8 KB  [dk][key]
  __shared__ h16 Ps[4 * 32 * 64];   // 16 KB  per-wave P
  const int tid  = threadIdx.x;
  const int wave = tid >> 6, lane = tid & 63;
  const int lr = lane & 15, lq = lane >> 4;
  const int b = blockIdx.z, h = blockIdx.y;
  const int q0 = blockIdx.x * 128;
  const long bh = (long)b * NHH + h;
  const h16* Qg = Qh + bh * NN * DKK;
  const h16* Kg = Kh + bh * NN * DKK;
  const h16* Vg = Vt + bh * DKK * NN;

#pragma unroll
  for (int r = 0; r < 4; ++r) {               // stage 128x64 Q once
    const int c = r * 256 + tid;
    gld16(Qs + c * 8, Qg + (long)(q0 + (c >> 3)) * DKK + (c & 7) * 8);
  }

  f32x4 acc[2][4] = {};
  float mrow[2][4], lsum[2][4];
#pragma unroll
  for (int a = 0; a < 2; ++a)
#pragma unroll
    for (int j = 0; j < 4; ++j) { mrow[a][j] = -3.0e38f; lsum[a][j] = 0.0f; }

  for (int kc = 0; kc < NN; kc += 64) {
#pragma unroll
    for (int r = 0; r < 2; ++r) {
      const int c = r * 256 + tid;
      const int row = c >> 3, sg = (c & 7) * 8;
      gld16(Ks  + c * 8, Kg + (long)(kc + row) * DKK + sg);
      gld16(Vts + c * 8, Vg + (long)row * NN + kc + sg);
    }
    __syncthreads();

    // S = Q K^T  (2 qm-frags x 4 kn-frags, DK=64 -> 2 mfma steps)
    f32x4 s[2][4] = {};
#pragma unroll
    for (int ks = 0; ks < 2; ++ks) {
      h16x8 aq[2], bk4[4];
#pragma unroll
      for (int qm = 0; qm < 2; ++qm)
        aq[qm] = *(const h16x8*)(Qs + (wave * 32 + qm * 16 + lr) * 64 + ks * 32 + lq * 8);
#pragma unroll
      for (int kn = 0; kn < 4; ++kn)
        bk4[kn] = *(const h16x8*)(Ks + (kn * 16 + lr) * 64 + ks * 32 + lq * 8);
#pragma unroll
      for (int qm = 0; qm < 2; ++qm)
#pragma unroll
        for (int kn = 0; kn < 4; ++kn)
          s[qm][kn] = __builtin_amdgcn_mfma_f32_16x16x32_f16(aq[qm], bk4[kn], s[qm][kn], 0, 0, 0);
    }

    // scale + spm bias, row-max
    float pm[2][4];
#pragma unroll
    for (int qm = 0; qm < 2; ++qm)
#pragma unroll
      for (int j = 0; j < 4; ++j) pm[qm][j] = -3.0e38f;
#pragma unroll
    for (int qm = 0; qm < 2; ++qm)
#pragma unroll
      for (int kn = 0; kn < 4; ++kn)
#pragma unroll
        for (int j = 0; j < 4; ++j) {
          const int q = q0 + wave * 32 + qm * 16 + lq * 4 + j;
          const int key = kc + kn * 16 + lr;
          float v = s[qm][kn][j] * 0.125f + spm[((long)b * NN + q) * NN + key];
          s[qm][kn][j] = v;
          pm[qm][j] = fmaxf(pm[qm][j], v);
        }
#pragma unroll
    for (int qm = 0; qm < 2; ++qm)
#pragma unroll
      for (int j = 0; j < 4; ++j) {
#pragma unroll
        for (int d = 1; d < 16; d <<= 1) pm[qm][j] = fmaxf(pm[qm][j], __shfl_xor(pm[qm][j], d));
      }
    // online-softmax update
    float corr[2][4];
#pragma unroll
    for (int qm = 0; qm < 2; ++qm)
#pragma unroll
      for (int j = 0; j < 4; ++j) {
        const float mn = fmaxf(mrow[qm][j], pm[qm][j]);
        corr[qm][j] = __expf(mrow[qm][j] - mn);
        mrow[qm][j] = mn;
        lsum[qm][j] *= corr[qm][j];
      }
    float rs[2][4] = {};
#pragma unroll
    for (int qm = 0; qm < 2; ++qm)
#pragma unroll
      for (int kn = 0; kn < 4; ++kn)
#pragma unroll
        for (int j = 0; j < 4; ++j) {
          const float pexp = __expf(s[qm][kn][j] - mrow[qm][j]);
          s[qm][kn][j] = pexp;
          rs[qm][j] += pexp;
        }
#pragma unroll
    for (int qm = 0; qm < 2; ++qm)
#pragma unroll
      for (int j = 0; j < 4; ++j) {
#pragma unroll
        for (int d = 1; d < 16; d <<= 1) rs[qm][j] += __shfl_xor(rs[qm][j], d);
        lsum[qm][j] += rs[qm][j];
      }
#pragma unroll
    for (int qm = 0; qm < 2; ++qm)
#pragma unroll
      for (int dn = 0; dn < 4; ++dn)
#pragma unroll
        for (int j = 0; j < 4; ++j) acc[qm][dn][j] *= corr[qm][j];

    // P (C-layout) -> LDS -> A-layout frags
#pragma unroll
    for (int qm = 0; qm < 2; ++qm)
#pragma unroll
      for (int kn = 0; kn < 4; ++kn)
#pragma unroll
        for (int j = 0; j < 4; ++j)
          Ps[wave * 2048 + (qm * 16 + lq * 4 + j) * 64 + kn * 16 + lr] = (h16)s[qm][kn][j];

    // O += P @ V
#pragma unroll
    for (int ks = 0; ks < 2; ++ks) {
      h16x8 ap[2], bv4[4];
#pragma unroll
      for (int qm = 0; qm < 2; ++qm)
        ap[qm] = *(const h16x8*)(Ps + wave * 2048 + (qm * 16 + lr) * 64 + ks * 32 + lq * 8);
#pragma unroll
      for (int dn = 0; dn < 4; ++dn)
        bv4[dn] = *(const h16x8*)(Vts + (dn * 16 + lr) * 64 + ks * 32 + lq * 8);
#pragma unroll
      for (int qm = 0; qm < 2; ++qm)
#pragma unroll
        for (int dn = 0; dn < 4; ++dn)
          acc[qm][dn] = __builtin_amdgcn_mfma_f32_16x16x32_f16(ap[qm], bv4[dn], acc[qm][dn], 0, 0, 0);
    }
    __syncthreads();
  }

  // normalize + write O as [B,N,D] f16 (concat heads)
  float rinv[2][4];
#pragma unroll
  for (int qm = 0; qm < 2; ++qm)
#pragma unroll
    for (int j = 0; j < 4; ++j) rinv[qm][j] = 1.0f / lsum[qm][j];
#pragma unroll
  for (int qm = 0; qm < 2; ++qm)
#pragma unroll
    for (int dn = 0; dn < 4; ++dn)
#pragma unroll
      for (int j = 0; j < 4; ++j) {
        const int q = q0 + wave * 32 + qm * 16 + lq * 4 + j;
        const int dk = dn * 16 + lr;
        Oh[((long)b * NN + q) * DD + h * DKK + dk] = (h16)(acc[qm][dn][j] * rinv[qm][j]);
      }
}

// ---------------- launch ----------------
extern "C" void kernel_launch(void* const* d_in, const int* in_sizes, int n_in,
                              void* d_out, int out_size, void* d_ws, size_t ws_size,
                              hipStream_t stream)
{
  const float* H   = (const float*)d_in[0];
  const float* spm = (const float*)d_in[1];
  const float* Wq  = (const float*)d_in[2];
  const float* bq  = (const float*)d_in[3];
  const float* Wk  = (const float*)d_in[4];
  const float* bk  = (const float*)d_in[5];
  const float* Wv  = (const float*)d_in[6];
  const float* bv  = (const float*)d_in[7];
  const float* Wo  = (const float*)d_in[8];
  const float* bo  = (const float*)d_in[9];
  const float* W1  = (const float*)d_in[10];
  const float* b1  = (const float*)d_in[11];
  const float* W2  = (const float*)d_in[12];
  const float* b2  = (const float*)d_in[13];
  float* out = (float*)d_out;

  char* p = (char*)d_ws;
  auto alloc = [&](size_t bytes) { char* r = p; p += (bytes + 255) & ~(size_t)255; return r; };
  h16* ln1   = (h16*)alloc((size_t)MM * DD * 2);        // 16 MB (reused as ln2)
  h16* wqkv  = (h16*)alloc((size_t)3 * DD * DD * 2);    //  6 MB
  h16* wo_t  = (h16*)alloc((size_t)DD * DD * 2);        //  2 MB
  h16* w1_t  = (h16*)alloc((size_t)DD * DFF * 2);       //  8 MB
  h16* w2_t  = (h16*)alloc((size_t)DFF * DD * 2);       //  8 MB
  h16* Qh    = (h16*)alloc((size_t)MM * DD * 2);        // 16 MB (contig 64MB Qh..Oh)
  h16* Kh    = (h16*)alloc((size_t)MM * DD * 2);        // 16 MB
  h16* Vt    = (h16*)alloc((size_t)MM * DD * 2);        // 16 MB (reused as hff)
  h16* Oh    = (h16*)alloc((size_t)MM * DD * 2);        // 16 MB
  float* x   = (float*)alloc((size_t)MM * DD * 4);      // 32 MB
  h16* ln2 = ln1;                                       // alias (ln1 dead after QKV GEMM)
  h16* hff = Qh;                                        // alias (Q/K/V/O dead after Wo GEMM)

  // 1) LN1
  ln_k<<<MM, 256, 0, stream>>>(H, ln1);
  // 2) weight transpose-casts to f16 B^T layouts
  tcast_k<<<dim3(2, 32, 16),  256, 0, stream>>>(Wq, wqkv,                 DD, DKK, (long)DD * DKK, (long)DKK * DD);
  tcast_k<<<dim3(2, 32, 16),  256, 0, stream>>>(Wk, wqkv + DD * DD,       DD, DKK, (long)DD * DKK, (long)DKK * DD);
  tcast_k<<<dim3(2, 32, 16),  256, 0, stream>>>(Wv, wqkv + 2 * DD * DD,   DD, DKK, (long)DD * DKK, (long)DKK * DD);
  tcast_k<<<dim3(32, 32, 1),  256, 0, stream>>>(Wo, wo_t, DD,  DD,  0, 0);
  tcast_k<<<dim3(128, 32, 1), 256, 0, stream>>>(W1, w1_t, DD,  DFF, 0, 0);
  tcast_k<<<dim3(32, 128, 1), 256, 0, stream>>>(W2, w2_t, DFF, DD,  0, 0);
  // 3) fused QKV projection (scatters Q,K [b,h,n,dk]; V transposed [b,h,dk,n])
  gemm_k<0><<<dim3(24, 64), 256, 0, stream>>>(ln1, wqkv, DD, 3 * DD, bq, bk, bv, Qh, Kh, Vt, nullptr, nullptr);
  // 4) attention
  attn_k<<<dim3(4, NHH, BB), 256, 0, stream>>>(Qh, Kh, Vt, spm, Oh);
  // 5) Wo GEMM + residual -> x (fp32)
  gemm_k<1><<<dim3(8, 64), 256, 0, stream>>>(Oh, wo_t, DD, DD, bo, nullptr, nullptr, nullptr, nullptr, nullptr, x, H);
  // 6) LN2
  ln_k<<<MM, 256, 0, stream>>>(x, ln2);
  // 7) FFN1 + ReLU -> hff (f16)
  gemm_k<2><<<dim3(32, 64), 256, 0, stream>>>(ln2, w1_t, DD, DFF, b1, nullptr, nullptr, hff, nullptr, nullptr, nullptr, nullptr);
  // 8) FFN2 + residual -> out (fp32)
  gemm_k<3><<<dim3(8, 64), 256, 0, stream>>>(hff, w2_t, DFF, DD, b2, nullptr, nullptr, nullptr, nullptr, nullptr, out, x);
}

// Round 4
// 559.246 us; speedup vs baseline: 1.1373x; 1.1373x over previous
//
#include <hip/hip_runtime.h>

// ---------------- problem constants ----------------
#define BB   16
#define NN   512
#define DD   1024
#define NHH  16
#define DKK  64
#define DFF  4096
#define MM   (BB*NN)     // 8192 rows

typedef _Float16 h16;
typedef h16  h16x8 __attribute__((ext_vector_type(8)));
typedef h16  h16x4 __attribute__((ext_vector_type(4)));
typedef float f32x4 __attribute__((ext_vector_type(4)));

#define AS1 __attribute__((address_space(1)))
#define AS3 __attribute__((address_space(3)))

__device__ __forceinline__ void gld16(h16* lds_dst, const h16* g_src) {
  // async global->LDS, 16B per lane; LDS dest must be lane-linear (wave-uniform base + lane*16)
  __builtin_amdgcn_global_load_lds((const AS1 void*)g_src, (AS3 void*)lds_dst, 16, 0, 0);
}

// ---------------- LayerNorm row kernel: fp32 [rows][1024] -> f16 ----------------
__global__ __launch_bounds__(256) void ln_k(const float* __restrict__ in, h16* __restrict__ out)
{
  const int row = blockIdx.x;
  const int tid = threadIdx.x;
  const float4 v = ((const float4*)(in + (long)row * DD))[tid];
  float s  = v.x + v.y + v.z + v.w;
  float ss = v.x*v.x + v.y*v.y + v.z*v.z + v.w*v.w;
#pragma unroll
  for (int d = 32; d > 0; d >>= 1) { s += __shfl_down(s, d); ss += __shfl_down(ss, d); }
  __shared__ float red[8];
  const int wv = tid >> 6, ln = tid & 63;
  if (ln == 0) { red[wv] = s; red[4 + wv] = ss; }
  __syncthreads();
  s  = red[0] + red[1] + red[2] + red[3];
  ss = red[4] + red[5] + red[6] + red[7];
  const float mean = s * (1.0f / DD);
  const float var  = ss * (1.0f / DD) - mean * mean;
  const float rstd = rsqrtf(var + 1e-5f);
  h16x4 o;
  o[0] = (h16)((v.x - mean) * rstd);
  o[1] = (h16)((v.y - mean) * rstd);
  o[2] = (h16)((v.z - mean) * rstd);
  o[3] = (h16)((v.w - mean) * rstd);
  ((h16x4*)(out + (long)row * DD))[tid] = o;
}

// ---------------- transpose-cast: src fp32 [R][C] -> dst f16 [C][R], batched ----------------
__global__ __launch_bounds__(256) void tcast_k(const float* __restrict__ src, h16* __restrict__ dst,
                                               int R, int C, long sB, long dB)
{
  __shared__ float tile[32][33];
  const float* s = src + (long)blockIdx.z * sB;
  h16* d = dst + (long)blockIdx.z * dB;
  const int c0 = blockIdx.x * 32, r0 = blockIdx.y * 32;
  const int tx = threadIdx.x & 31, ty = threadIdx.x >> 5;   // 32 x 8
#pragma unroll
  for (int i = 0; i < 32; i += 8)
    tile[ty + i][tx] = s[(long)(r0 + ty + i) * C + c0 + tx];
  __syncthreads();
#pragma unroll
  for (int i = 0; i < 32; i += 8)
    d[(long)(c0 + ty + i) * R + r0 + tx] = (h16)tile[tx][ty + i];
}

// ---------------- f16 MFMA GEMM: C[M][Nc] = A[M][K] * Bt[Nc][K]^T ----------------
// depth-2 pipelined K-loop (3 LDS bufs, counted vmcnt), XOR-swizzled LDS.
// EPI 0: QK scatter (+bias)  EPI 1: x = C+bo+H  EPI 2: hff = relu(C+b1)
// EPI 3: out = C+b2+x        EPI 4: Vt scatter (row=dk-index, col=token; bias over row)
template<int EPI>
__global__ __launch_bounds__(256) void gemm_k(
    const h16* __restrict__ A, const h16* __restrict__ Bt, int K, int Nc,
    const float* __restrict__ bias0, const float* __restrict__ bias1,
    h16* __restrict__ o0, h16* __restrict__ o1,
    float* __restrict__ of, const float* __restrict__ addsrc)
{
  __shared__ h16 Asb[3 * 4096];   // 3 bufs x 128x32 f16 = 24 KB
  __shared__ h16 Bsb[3 * 4096];   // 24 KB
  const int tid  = threadIdx.x;
  const int wave = tid >> 6, lane = tid & 63;
  const int lr = lane & 15, lq = lane >> 4;
  const int m0 = blockIdx.y * 128, n0 = blockIdx.x * 128;
  const int wr = (wave >> 1) * 64, wc = (wave & 1) * 64;

  // staging: chunk c (16B) -> LDS linear c*16; global slot XOR-swizzled
  // swizzle (involution): chunk' = chunk ^ ((chunk>>3)&3)  [byte bits 5:4 ^= row bits 2:1]
  const int c0 = tid,       r0 = c0 >> 2, s0 = ((c0 & 3) ^ ((c0 >> 3) & 3)) * 8;
  const int c1 = tid + 256, r1 = c1 >> 2, s1 = ((c1 & 3) ^ ((c1 >> 3) & 3)) * 8;

  // fragment read offsets (h16 elems): row*32 + (lq ^ ((row>>1)&3))*8
  int offA[4], offB[4];
#pragma unroll
  for (int i = 0; i < 4; ++i) {
    const int ra = wr + i * 16 + lr;
    const int rb = wc + i * 16 + lr;
    offA[i] = ra * 32 + (lq ^ ((ra >> 1) & 3)) * 8;
    offB[i] = rb * 32 + (lq ^ ((rb >> 1) & 3)) * 8;
  }

  f32x4 acc[4][4] = {};

  auto STAGE = [&](int k0, int bi) {
    h16* Ad = Asb + bi * 4096;
    h16* Bd = Bsb + bi * 4096;
    gld16(Ad + c0 * 8, A  + (long)(m0 + r0) * K + k0 + s0);
    gld16(Ad + c1 * 8, A  + (long)(m0 + r1) * K + k0 + s1);
    gld16(Bd + c0 * 8, Bt + (long)(n0 + r0) * K + k0 + s0);
    gld16(Bd + c1 * 8, Bt + (long)(n0 + r1) * K + k0 + s1);
  };

  const int nt = K >> 5;           // K/32 tiles (>=32 here)
  STAGE(0, 0);
  STAGE(32, 1);
  int cur = 0, nxt = 2;

  for (int t = 0; t < nt; ++t) {
    if (t + 2 < nt) {
      STAGE((t + 2) << 5, nxt);
      nxt = (nxt == 2) ? 0 : nxt + 1;
    }
    // per-wave wait for tile t's 4 loads (2 newer tiles = 8 ops may stay in flight)
    if (t + 2 < nt)      asm volatile("s_waitcnt vmcnt(8)" ::: "memory");
    else if (t + 1 < nt) asm volatile("s_waitcnt vmcnt(4)" ::: "memory");
    else                 asm volatile("s_waitcnt vmcnt(0)" ::: "memory");
    __builtin_amdgcn_sched_barrier(0);
    __builtin_amdgcn_s_barrier();            // publish: all waves' tile-t loads landed
    asm volatile("" ::: "memory");

    const h16* Ac = Asb + cur * 4096;
    const h16* Bc = Bsb + cur * 4096;
    h16x8 af[4], bf[4];
#pragma unroll
    for (int i = 0; i < 4; ++i) {
      af[i] = *(const h16x8*)(Ac + offA[i]);
      bf[i] = *(const h16x8*)(Bc + offB[i]);
    }
    asm volatile("s_waitcnt lgkmcnt(0)" ::: "memory");
    __builtin_amdgcn_sched_barrier(0);
    __builtin_amdgcn_s_barrier();            // all waves done reading buf -> re-stageable
    asm volatile("" ::: "memory");

    __builtin_amdgcn_s_setprio(1);
#pragma unroll
    for (int i = 0; i < 4; ++i)
#pragma unroll
      for (int j = 0; j < 4; ++j)
        acc[i][j] = __builtin_amdgcn_mfma_f32_16x16x32_f16(af[i], bf[j], acc[i][j], 0, 0, 0);
    __builtin_amdgcn_s_setprio(0);

    cur = (cur == 2) ? 0 : cur + 1;
  }

  // epilogue: C/D layout row = (lane>>4)*4 + reg, col = lane&15
#pragma unroll
  for (int i = 0; i < 4; ++i) {
#pragma unroll
    for (int jn = 0; jn < 4; ++jn) {
#pragma unroll
      for (int j = 0; j < 4; ++j) {
        const int m   = m0 + wr + i * 16 + lq * 4 + j;
        const int col = n0 + wc + jn * 16 + lr;
        float v = acc[i][jn][j];
        if constexpr (EPI == 0) {
          const int w  = col >> 10;            // 0=Q 1=K (block-uniform)
          const int hh = (col >> 6) & 15, kk = col & 63;
          const int bidx = m >> 9, nq = m & 511;
          const int bcol = col & 1023;
          if (w == 0) o0[(((long)bidx * NHH + hh) * NN + nq) * DKK + kk] = (h16)(v + bias0[bcol]);
          else        o1[(((long)bidx * NHH + hh) * NN + nq) * DKK + kk] = (h16)(v + bias1[bcol]);
        } else if constexpr (EPI == 1) {
          of[(long)m * Nc + col] = v + bias0[col] + addsrc[(long)m * Nc + col];
        } else if constexpr (EPI == 2) {
          o0[(long)m * Nc + col] = (h16)fmaxf(v + bias0[col], 0.0f);
        } else if constexpr (EPI == 3) {
          of[(long)m * Nc + col] = v + bias0[col] + addsrc[(long)m * Nc + col];
        } else {
          // EPI 4: m = h*64+kk (dk-row), col = token; coalesced over col
          const int bidx = col >> 9, nq = col & 511;
          o0[(((long)bidx * NHH + (m >> 6)) * DKK + (m & 63)) * NN + nq] = (h16)(v + bias0[m]);
        }
      }
    }
  }
}

// ---------------- flash attention: per (b,h), 128 q-rows/block, 64-key chunks ----------------
__global__ __launch_bounds__(256) void attn_k(
    const h16* __restrict__ Qh, const h16* __restrict__ Kh, const h16* __restrict__ Vt,
    const float* __restrict__ spm, h16* __restrict__ Oh)
{
  __shared__ h16 Qs[128 * 64];      // 16 KB
  __shared__ h16 Ks[64 * 64];       //  8 KB  [key][dk]
  __shared__ h16 Vts[64 * 64];      //  8 KB  [dk][key]
  __shared__ h16 Ps[4 * 32 * 64];   // 16 KB  per-wave P
  const int tid  = threadIdx.x;
  const int wave = tid >> 6, lane = tid & 63;
  const int lr = lane & 15, lq = lane >> 4;
  const int b = blockIdx.z, h = blockIdx.y;
  const int q0 = blockIdx.x * 128;
  const long bh = (long)b * NHH + h;
  const h16* Qg = Qh + bh * NN * DKK;
  const h16* Kg = Kh + bh * NN * DKK;
  const h16* Vg = Vt + bh * DKK * NN;

#pragma unroll
  for (int r = 0; r < 4; ++r) {               // stage 128x64 Q once
    const int c = r * 256 + tid;
    gld16(Qs + c * 8, Qg + (long)(q0 + (c >> 3)) * DKK + (c & 7) * 8);
  }

  f32x4 acc[2][4] = {};
  float mrow[2][4], lsum[2][4];
#pragma unroll
  for (int a = 0; a < 2; ++a)
#pragma unroll
    for (int j = 0; j < 4; ++j) { mrow[a][j] = -3.0e38f; lsum[a][j] = 0.0f; }

  for (int kc = 0; kc < NN; kc += 64) {
#pragma unroll
    for (int r = 0; r < 2; ++r) {
      const int c = r * 256 + tid;
      const int row = c >> 3, sg = (c & 7) * 8;
      gld16(Ks  + c * 8, Kg + (long)(kc + row) * DKK + sg);
      gld16(Vts + c * 8, Vg + (long)row * NN + kc + sg);
    }
    __syncthreads();

    // S = Q K^T  (2 qm-frags x 4 kn-frags, DK=64 -> 2 mfma steps)
    f32x4 s[2][4] = {};
#pragma unroll
    for (int ks = 0; ks < 2; ++ks) {
      h16x8 aq[2], bk4[4];
#pragma unroll
      for (int qm = 0; qm < 2; ++qm)
        aq[qm] = *(const h16x8*)(Qs + (wave * 32 + qm * 16 + lr) * 64 + ks * 32 + lq * 8);
#pragma unroll
      for (int kn = 0; kn < 4; ++kn)
        bk4[kn] = *(const h16x8*)(Ks + (kn * 16 + lr) * 64 + ks * 32 + lq * 8);
#pragma unroll
      for (int qm = 0; qm < 2; ++qm)
#pragma unroll
        for (int kn = 0; kn < 4; ++kn)
          s[qm][kn] = __builtin_amdgcn_mfma_f32_16x16x32_f16(aq[qm], bk4[kn], s[qm][kn], 0, 0, 0);
    }

    // scale + spm bias, row-max
    float pm[2][4];
#pragma unroll
    for (int qm = 0; qm < 2; ++qm)
#pragma unroll
      for (int j = 0; j < 4; ++j) pm[qm][j] = -3.0e38f;
#pragma unroll
    for (int qm = 0; qm < 2; ++qm)
#pragma unroll
      for (int kn = 0; kn < 4; ++kn)
#pragma unroll
        for (int j = 0; j < 4; ++j) {
          const int q = q0 + wave * 32 + qm * 16 + lq * 4 + j;
          const int key = kc + kn * 16 + lr;
          float v = s[qm][kn][j] * 0.125f + spm[((long)b * NN + q) * NN + key];
          s[qm][kn][j] = v;
          pm[qm][j] = fmaxf(pm[qm][j], v);
        }
#pragma unroll
    for (int qm = 0; qm < 2; ++qm)
#pragma unroll
      for (int j = 0; j < 4; ++j) {
#pragma unroll
        for (int d = 1; d < 16; d <<= 1) pm[qm][j] = fmaxf(pm[qm][j], __shfl_xor(pm[qm][j], d));
      }
    // online-softmax update
    float corr[2][4];
#pragma unroll
    for (int qm = 0; qm < 2; ++qm)
#pragma unroll
      for (int j = 0; j < 4; ++j) {
        const float mn = fmaxf(mrow[qm][j], pm[qm][j]);
        corr[qm][j] = __expf(mrow[qm][j] - mn);
        mrow[qm][j] = mn;
        lsum[qm][j] *= corr[qm][j];
      }
    float rs[2][4] = {};
#pragma unroll
    for (int qm = 0; qm < 2; ++qm)
#pragma unroll
      for (int kn = 0; kn < 4; ++kn)
#pragma unroll
        for (int j = 0; j < 4; ++j) {
          const float pexp = __expf(s[qm][kn][j] - mrow[qm][j]);
          s[qm][kn][j] = pexp;
          rs[qm][j] += pexp;
        }
#pragma unroll
    for (int qm = 0; qm < 2; ++qm)
#pragma unroll
      for (int j = 0; j < 4; ++j) {
#pragma unroll
        for (int d = 1; d < 16; d <<= 1) rs[qm][j] += __shfl_xor(rs[qm][j], d);
        lsum[qm][j] += rs[qm][j];
      }
#pragma unroll
    for (int qm = 0; qm < 2; ++qm)
#pragma unroll
      for (int dn = 0; dn < 4; ++dn)
#pragma unroll
        for (int j = 0; j < 4; ++j) acc[qm][dn][j] *= corr[qm][j];

    // P (C-layout) -> LDS -> A-layout frags
#pragma unroll
    for (int qm = 0; qm < 2; ++qm)
#pragma unroll
      for (int kn = 0; kn < 4; ++kn)
#pragma unroll
        for (int j = 0; j < 4; ++j)
          Ps[wave * 2048 + (qm * 16 + lq * 4 + j) * 64 + kn * 16 + lr] = (h16)s[qm][kn][j];

    // O += P @ V
#pragma unroll
    for (int ks = 0; ks < 2; ++ks) {
      h16x8 ap[2], bv4[4];
#pragma unroll
      for (int qm = 0; qm < 2; ++qm)
        ap[qm] = *(const h16x8*)(Ps + wave * 2048 + (qm * 16 + lr) * 64 + ks * 32 + lq * 8);
#pragma unroll
      for (int dn = 0; dn < 4; ++dn)
        bv4[dn] = *(const h16x8*)(Vts + (dn * 16 + lr) * 64 + ks * 32 + lq * 8);
#pragma unroll
      for (int qm = 0; qm < 2; ++qm)
#pragma unroll
        for (int dn = 0; dn < 4; ++dn)
          acc[qm][dn] = __builtin_amdgcn_mfma_f32_16x16x32_f16(ap[qm], bv4[dn], acc[qm][dn], 0, 0, 0);
    }
    __syncthreads();
  }

  // normalize + write O as [B,N,D] f16 (concat heads)
  float rinv[2][4];
#pragma unroll
  for (int qm = 0; qm < 2; ++qm)
#pragma unroll
    for (int j = 0; j < 4; ++j) rinv[qm][j] = 1.0f / lsum[qm][j];
#pragma unroll
  for (int qm = 0; qm < 2; ++qm)
#pragma unroll
    for (int dn = 0; dn < 4; ++dn)
#pragma unroll
      for (int j = 0; j < 4; ++j) {
        const int q = q0 + wave * 32 + qm * 16 + lq * 4 + j;
        const int dk = dn * 16 + lr;
        Oh[((long)b * NN + q) * DD + h * DKK + dk] = (h16)(acc[qm][dn][j] * rinv[qm][j]);
      }
}

// ---------------- launch ----------------
extern "C" void kernel_launch(void* const* d_in, const int* in_sizes, int n_in,
                              void* d_out, int out_size, void* d_ws, size_t ws_size,
                              hipStream_t stream)
{
  const float* H   = (const float*)d_in[0];
  const float* spm = (const float*)d_in[1];
  const float* Wq  = (const float*)d_in[2];
  const float* bq  = (const float*)d_in[3];
  const float* Wk  = (const float*)d_in[4];
  const float* bk  = (const float*)d_in[5];
  const float* Wv  = (const float*)d_in[6];
  const float* bv  = (const float*)d_in[7];
  const float* Wo  = (const float*)d_in[8];
  const float* bo  = (const float*)d_in[9];
  const float* W1  = (const float*)d_in[10];
  const float* b1  = (const float*)d_in[11];
  const float* W2  = (const float*)d_in[12];
  const float* b2  = (const float*)d_in[13];
  float* out = (float*)d_out;

  char* p = (char*)d_ws;
  auto alloc = [&](size_t bytes) { char* r = p; p += (bytes + 255) & ~(size_t)255; return r; };
  h16* ln1   = (h16*)alloc((size_t)MM * DD * 2);        // 16 MB (reused as ln2)
  h16* wqkv  = (h16*)alloc((size_t)3 * DD * DD * 2);    //  6 MB
  h16* wo_t  = (h16*)alloc((size_t)DD * DD * 2);        //  2 MB
  h16* w1_t  = (h16*)alloc((size_t)DD * DFF * 2);       //  8 MB
  h16* w2_t  = (h16*)alloc((size_t)DFF * DD * 2);       //  8 MB
  h16* Qh    = (h16*)alloc((size_t)MM * DD * 2);        // 16 MB (contig 64MB Qh..Oh)
  h16* Kh    = (h16*)alloc((size_t)MM * DD * 2);        // 16 MB
  h16* Vt    = (h16*)alloc((size_t)MM * DD * 2);        // 16 MB (reused as hff)
  h16* Oh    = (h16*)alloc((size_t)MM * DD * 2);        // 16 MB
  float* x   = (float*)alloc((size_t)MM * DD * 4);      // 32 MB
  h16* ln2 = ln1;                                       // alias (ln1 dead after QKV+VT GEMMs)
  h16* hff = Qh;                                        // alias (Q/K/V/O dead after Wo GEMM)

  // 1) LN1
  ln_k<<<MM, 256, 0, stream>>>(H, ln1);
  // 2) weight transpose-casts to f16 B^T layouts
  tcast_k<<<dim3(2, 32, 16),  256, 0, stream>>>(Wq, wqkv,                 DD, DKK, (long)DD * DKK, (long)DKK * DD);
  tcast_k<<<dim3(2, 32, 16),  256, 0, stream>>>(Wk, wqkv + DD * DD,       DD, DKK, (long)DD * DKK, (long)DKK * DD);
  tcast_k<<<dim3(2, 32, 16),  256, 0, stream>>>(Wv, wqkv + 2 * DD * DD,   DD, DKK, (long)DD * DKK, (long)DKK * DD);
  tcast_k<<<dim3(32, 32, 1),  256, 0, stream>>>(Wo, wo_t, DD,  DD,  0, 0);
  tcast_k<<<dim3(128, 32, 1), 256, 0, stream>>>(W1, w1_t, DD,  DFF, 0, 0);
  tcast_k<<<dim3(32, 128, 1), 256, 0, stream>>>(W2, w2_t, DFF, DD,  0, 0);
  // 3a) QK projection (scatters Q,K [b,h,n,dk])
  gemm_k<0><<<dim3(16, 64), 256, 0, stream>>>(ln1, wqkv, DD, 2 * DD, bq, bk, Qh, Kh, nullptr, nullptr);
  // 3b) V^T projection: A = Wv^T-part [dk-rows=1024][d], Bt = ln1 -> Vt [b,h,dk,n] coalesced
  gemm_k<4><<<dim3(64, 8), 256, 0, stream>>>(wqkv + 2 * DD * DD, ln1, DD, MM, bv, nullptr, Vt, nullptr, nullptr, nullptr);
  // 4) attention
  attn_k<<<dim3(4, NHH, BB), 256, 0, stream>>>(Qh, Kh, Vt, spm, Oh);
  // 5) Wo GEMM + residual -> x (fp32)
  gemm_k<1><<<dim3(8, 64), 256, 0, stream>>>(Oh, wo_t, DD, DD, bo, nullptr, nullptr, nullptr, x, H);
  // 6) LN2
  ln_k<<<MM, 256, 0, stream>>>(x, ln2);
  // 7) FFN1 + ReLU -> hff (f16)
  gemm_k<2><<<dim3(32, 64), 256, 0, stream>>>(ln2, w1_t, DD, DFF, b1, nullptr, hff, nullptr, nullptr, nullptr);
  // 8) FFN2 + residual -> out (fp32)
  gemm_k<3><<<dim3(8, 64), 256, 0, stream>>>(hff, w2_t, DFF, DD, b2, nullptr, nullptr, nullptr, out, x);
}

// Round 5
// 548.565 us; speedup vs baseline: 1.1595x; 1.0195x over previous
//
#include <hip/hip_runtime.h>

// ---------------- problem constants ----------------
#define BB   16
#define NN   512
#define DD   1024
#define NHH  16
#define DKK  64
#define DFF  4096
#define MM   (BB*NN)     // 8192 rows

typedef _Float16 h16;
typedef h16  h16x8 __attribute__((ext_vector_type(8)));
typedef h16  h16x4 __attribute__((ext_vector_type(4)));
typedef float f32x4 __attribute__((ext_vector_type(4)));

#define AS1 __attribute__((address_space(1)))
#define AS3 __attribute__((address_space(3)))

__device__ __forceinline__ void gld16(h16* lds_dst, const h16* g_src) {
  // async global->LDS, 16B per lane; LDS dest must be lane-linear (wave-uniform base + lane*16)
  __builtin_amdgcn_global_load_lds((const AS1 void*)g_src, (AS3 void*)lds_dst, 16, 0, 0);
}

// ---------------- LayerNorm row kernel: fp32 [rows][1024] -> f16 ----------------
__global__ __launch_bounds__(256) void ln_k(const float* __restrict__ in, h16* __restrict__ out)
{
  const int row = blockIdx.x;
  const int tid = threadIdx.x;
  const float4 v = ((const float4*)(in + (long)row * DD))[tid];
  float s  = v.x + v.y + v.z + v.w;
  float ss = v.x*v.x + v.y*v.y + v.z*v.z + v.w*v.w;
#pragma unroll
  for (int d = 32; d > 0; d >>= 1) { s += __shfl_down(s, d); ss += __shfl_down(ss, d); }
  __shared__ float red[8];
  const int wv = tid >> 6, ln = tid & 63;
  if (ln == 0) { red[wv] = s; red[4 + wv] = ss; }
  __syncthreads();
  s  = red[0] + red[1] + red[2] + red[3];
  ss = red[4] + red[5] + red[6] + red[7];
  const float mean = s * (1.0f / DD);
  const float var  = ss * (1.0f / DD) - mean * mean;
  const float rstd = rsqrtf(var + 1e-5f);
  h16x4 o;
  o[0] = (h16)((v.x - mean) * rstd);
  o[1] = (h16)((v.y - mean) * rstd);
  o[2] = (h16)((v.z - mean) * rstd);
  o[3] = (h16)((v.w - mean) * rstd);
  ((h16x4*)(out + (long)row * DD))[tid] = o;
}

// ---------------- transpose-cast: src fp32 [R][C] -> dst f16 [C][R], batched ----------------
__global__ __launch_bounds__(256) void tcast_k(const float* __restrict__ src, h16* __restrict__ dst,
                                               int R, int C, long sB, long dB)
{
  __shared__ float tile[32][33];
  const float* s = src + (long)blockIdx.z * sB;
  h16* d = dst + (long)blockIdx.z * dB;
  const int c0 = blockIdx.x * 32, r0 = blockIdx.y * 32;
  const int tx = threadIdx.x & 31, ty = threadIdx.x >> 5;   // 32 x 8
#pragma unroll
  for (int i = 0; i < 32; i += 8)
    tile[ty + i][tx] = s[(long)(r0 + ty + i) * C + c0 + tx];
  __syncthreads();
#pragma unroll
  for (int i = 0; i < 32; i += 8)
    d[(long)(c0 + ty + i) * R + r0 + tx] = (h16)tile[tx][ty + i];
}

// ---------------- f16 MFMA GEMM: C[M][Nc] = A[M][K] * Bt[Nc][K]^T ----------------
// depth-2 pipelined K-loop (3 LDS bufs, counted vmcnt), XOR-swizzled LDS,
// XCD-banded block remap (each XCD owns an m-band, sweeps n fastest).
// EPI 0: QK scatter (+bias)  EPI 1: x = C+bo+H  EPI 2: hff = relu(C+b1)
// EPI 3: out = C+b2+x        EPI 4: Vt scatter (row=dk-index, col=token; bias over row)
template<int EPI>
__global__ __launch_bounds__(256) void gemm_k(
    const h16* __restrict__ A, const h16* __restrict__ Bt, int K, int Nc,
    const float* __restrict__ bias0, const float* __restrict__ bias1,
    h16* __restrict__ o0, h16* __restrict__ o1,
    float* __restrict__ of, const float* __restrict__ addsrc)
{
  __shared__ h16 Asb[3 * 4096];   // 3 bufs x 128x32 f16 = 24 KB
  __shared__ h16 Bsb[3 * 4096];   // 24 KB
  const int tid  = threadIdx.x;
  const int wave = tid >> 6, lane = tid & 63;
  const int lr = lane & 15, lq = lane >> 4;

  // XCD-banded remap: orig%8 ~ XCD (round-robin dispatch); band of Ny/8 m-panels
  // per XCD, n fastest within the band. Bijective (Ny % 8 == 0 for all launches).
  const int nxw = gridDim.x, nyw = gridDim.y;
  const int orig = blockIdx.x + nxw * blockIdx.y;
  const int xcd = orig & 7, sseq = orig >> 3;
  const int by = xcd * (nyw >> 3) + sseq / nxw;
  const int bx = sseq % nxw;
  const int m0 = by * 128, n0 = bx * 128;
  const int wr = (wave >> 1) * 64, wc = (wave & 1) * 64;

  // staging: chunk c (16B) -> LDS linear c*16; global slot XOR-swizzled
  // swizzle (involution): chunk' = chunk ^ ((chunk>>3)&3)  [byte bits 5:4 ^= row bits 2:1]
  const int c0 = tid,       r0 = c0 >> 2, s0 = ((c0 & 3) ^ ((c0 >> 3) & 3)) * 8;
  const int c1 = tid + 256, r1 = c1 >> 2, s1 = ((c1 & 3) ^ ((c1 >> 3) & 3)) * 8;

  // fragment read offsets (h16 elems): row*32 + (lq ^ ((row>>1)&3))*8
  int offA[4], offB[4];
#pragma unroll
  for (int i = 0; i < 4; ++i) {
    const int ra = wr + i * 16 + lr;
    const int rb = wc + i * 16 + lr;
    offA[i] = ra * 32 + (lq ^ ((ra >> 1) & 3)) * 8;
    offB[i] = rb * 32 + (lq ^ ((rb >> 1) & 3)) * 8;
  }

  f32x4 acc[4][4] = {};

  auto STAGE = [&](int k0, int bi) {
    h16* Ad = Asb + bi * 4096;
    h16* Bd = Bsb + bi * 4096;
    gld16(Ad + c0 * 8, A  + (long)(m0 + r0) * K + k0 + s0);
    gld16(Ad + c1 * 8, A  + (long)(m0 + r1) * K + k0 + s1);
    gld16(Bd + c0 * 8, Bt + (long)(n0 + r0) * K + k0 + s0);
    gld16(Bd + c1 * 8, Bt + (long)(n0 + r1) * K + k0 + s1);
  };

  const int nt = K >> 5;           // K/32 tiles (>=32 here)
  STAGE(0, 0);
  STAGE(32, 1);
  int cur = 0, nxt = 2;

  for (int t = 0; t < nt; ++t) {
    if (t + 2 < nt) {
      STAGE((t + 2) << 5, nxt);
      nxt = (nxt == 2) ? 0 : nxt + 1;
    }
    // per-wave wait for tile t's 4 loads (newer prefetches stay in flight)
    if (t + 2 < nt)      asm volatile("s_waitcnt vmcnt(8)" ::: "memory");
    else if (t + 1 < nt) asm volatile("s_waitcnt vmcnt(4)" ::: "memory");
    else                 asm volatile("s_waitcnt vmcnt(0)" ::: "memory");
    __builtin_amdgcn_sched_barrier(0);
    __builtin_amdgcn_s_barrier();            // publish: all waves' tile-t loads landed
    asm volatile("" ::: "memory");

    const h16* Ac = Asb + cur * 4096;
    const h16* Bc = Bsb + cur * 4096;
    h16x8 af[4], bf[4];
#pragma unroll
    for (int i = 0; i < 4; ++i) {
      af[i] = *(const h16x8*)(Ac + offA[i]);
      bf[i] = *(const h16x8*)(Bc + offB[i]);
    }
    // no explicit lgkm fence here: compiler emits fine-grained lgkmcnt so the
    // first MFMAs overlap the tail ds_reads (m97 behavior).
    __builtin_amdgcn_s_setprio(1);
#pragma unroll
    for (int i = 0; i < 4; ++i)
#pragma unroll
      for (int j = 0; j < 4; ++j)
        acc[i][j] = __builtin_amdgcn_mfma_f32_16x16x32_f16(af[i], bf[j], acc[i][j], 0, 0, 0);
    __builtin_amdgcn_s_setprio(0);

    // free the buffer: LDS reads are long complete (MFMAs consumed them), so
    // this lgkmcnt is non-blocking; raw s_barrier avoids __syncthreads' vmcnt(0) drain.
    asm volatile("s_waitcnt lgkmcnt(0)" ::: "memory");
    __builtin_amdgcn_sched_barrier(0);
    __builtin_amdgcn_s_barrier();
    asm volatile("" ::: "memory");

    cur = (cur == 2) ? 0 : cur + 1;
  }

  // epilogue: C/D layout row = (lane>>4)*4 + reg, col = lane&15
#pragma unroll
  for (int i = 0; i < 4; ++i) {
#pragma unroll
    for (int jn = 0; jn < 4; ++jn) {
#pragma unroll
      for (int j = 0; j < 4; ++j) {
        const int m   = m0 + wr + i * 16 + lq * 4 + j;
        const int col = n0 + wc + jn * 16 + lr;
        float v = acc[i][jn][j];
        if constexpr (EPI == 0) {
          const int w  = col >> 10;            // 0=Q 1=K (block-uniform)
          const int hh = (col >> 6) & 15, kk = col & 63;
          const int bidx = m >> 9, nq = m & 511;
          const int bcol = col & 1023;
          if (w == 0) o0[(((long)bidx * NHH + hh) * NN + nq) * DKK + kk] = (h16)(v + bias0[bcol]);
          else        o1[(((long)bidx * NHH + hh) * NN + nq) * DKK + kk] = (h16)(v + bias1[bcol]);
        } else if constexpr (EPI == 1) {
          of[(long)m * Nc + col] = v + bias0[col] + addsrc[(long)m * Nc + col];
        } else if constexpr (EPI == 2) {
          o0[(long)m * Nc + col] = (h16)fmaxf(v + bias0[col], 0.0f);
        } else if constexpr (EPI == 3) {
          of[(long)m * Nc + col] = v + bias0[col] + addsrc[(long)m * Nc + col];
        } else {
          // EPI 4: m = h*64+kk (dk-row), col = token; coalesced over col
          const int bidx = col >> 9, nq = col & 511;
          o0[(((long)bidx * NHH + (m >> 6)) * DKK + (m & 63)) * NN + nq] = (h16)(v + bias0[m]);
        }
      }
    }
  }
}

// ---------------- flash attention: per (b,h), 128 q-rows/block, 64-key chunks ----------------
__global__ __launch_bounds__(256) void attn_k(
    const h16* __restrict__ Qh, const h16* __restrict__ Kh, const h16* __restrict__ Vt,
    const float* __restrict__ spm, h16* __restrict__ Oh)
{
  __shared__ h16 Qs[128 * 64];      // 16 KB
  __shared__ h16 Ks[64 * 64];       //  8 KB  [key][dk]
  __shared__ h16 Vts[64 * 64];      //  8 KB  [dk][key]
  __shared__ h16 Ps[4 * 32 * 64];   // 16 KB  per-wave P
  const int tid  = threadIdx.x;
  const int wave = tid >> 6, lane = tid & 63;
  const int lr = lane & 15, lq = lane >> 4;
  const int b = blockIdx.z, h = blockIdx.y;
  const int q0 = blockIdx.x * 128;
  const long bh = (long)b * NHH + h;
  const h16* Qg = Qh + bh * NN * DKK;
  const h16* Kg = Kh + bh * NN * DKK;
  const h16* Vg = Vt + bh * DKK * NN;

#pragma unroll
  for (int r = 0; r < 4; ++r) {               // stage 128x64 Q once
    const int c = r * 256 + tid;
    gld16(Qs + c * 8, Qg + (long)(q0 + (c >> 3)) * DKK + (c & 7) * 8);
  }

  f32x4 acc[2][4] = {};
  float mrow[2][4], lsum[2][4];
#pragma unroll
  for (int a = 0; a < 2; ++a)
#pragma unroll
    for (int j = 0; j < 4; ++j) { mrow[a][j] = -3.0e38f; lsum[a][j] = 0.0f; }

  for (int kc = 0; kc < NN; kc += 64) {
#pragma unroll
    for (int r = 0; r < 2; ++r) {
      const int c = r * 256 + tid;
      const int row = c >> 3, sg = (c & 7) * 8;
      gld16(Ks  + c * 8, Kg + (long)(kc + row) * DKK + sg);
      gld16(Vts + c * 8, Vg + (long)row * NN + kc + sg);
    }
    __syncthreads();

    // S = Q K^T  (2 qm-frags x 4 kn-frags, DK=64 -> 2 mfma steps)
    f32x4 s[2][4] = {};
#pragma unroll
    for (int ks = 0; ks < 2; ++ks) {
      h16x8 aq[2], bk4[4];
#pragma unroll
      for (int qm = 0; qm < 2; ++qm)
        aq[qm] = *(const h16x8*)(Qs + (wave * 32 + qm * 16 + lr) * 64 + ks * 32 + lq * 8);
#pragma unroll
      for (int kn = 0; kn < 4; ++kn)
        bk4[kn] = *(const h16x8*)(Ks + (kn * 16 + lr) * 64 + ks * 32 + lq * 8);
#pragma unroll
      for (int qm = 0; qm < 2; ++qm)
#pragma unroll
        for (int kn = 0; kn < 4; ++kn)
          s[qm][kn] = __builtin_amdgcn_mfma_f32_16x16x32_f16(aq[qm], bk4[kn], s[qm][kn], 0, 0, 0);
    }

    // scale + spm bias, row-max
    float pm[2][4];
#pragma unroll
    for (int qm = 0; qm < 2; ++qm)
#pragma unroll
      for (int j = 0; j < 4; ++j) pm[qm][j] = -3.0e38f;
#pragma unroll
    for (int qm = 0; qm < 2; ++qm)
#pragma unroll
      for (int kn = 0; kn < 4; ++kn)
#pragma unroll
        for (int j = 0; j < 4; ++j) {
          const int q = q0 + wave * 32 + qm * 16 + lq * 4 + j;
          const int key = kc + kn * 16 + lr;
          float v = s[qm][kn][j] * 0.125f + spm[((long)b * NN + q) * NN + key];
          s[qm][kn][j] = v;
          pm[qm][j] = fmaxf(pm[qm][j], v);
        }
#pragma unroll
    for (int qm = 0; qm < 2; ++qm)
#pragma unroll
      for (int j = 0; j < 4; ++j) {
#pragma unroll
        for (int d = 1; d < 16; d <<= 1) pm[qm][j] = fmaxf(pm[qm][j], __shfl_xor(pm[qm][j], d));
      }
    // online-softmax update
    float corr[2][4];
#pragma unroll
    for (int qm = 0; qm < 2; ++qm)
#pragma unroll
      for (int j = 0; j < 4; ++j) {
        const float mn = fmaxf(mrow[qm][j], pm[qm][j]);
        corr[qm][j] = __expf(mrow[qm][j] - mn);
        mrow[qm][j] = mn;
        lsum[qm][j] *= corr[qm][j];
      }
    float rs[2][4] = {};
#pragma unroll
    for (int qm = 0; qm < 2; ++qm)
#pragma unroll
      for (int kn = 0; kn < 4; ++kn)
#pragma unroll
        for (int j = 0; j < 4; ++j) {
          const float pexp = __expf(s[qm][kn][j] - mrow[qm][j]);
          s[qm][kn][j] = pexp;
          rs[qm][j] += pexp;
        }
#pragma unroll
    for (int qm = 0; qm < 2; ++qm)
#pragma unroll
      for (int j = 0; j < 4; ++j) {
#pragma unroll
        for (int d = 1; d < 16; d <<= 1) rs[qm][j] += __shfl_xor(rs[qm][j], d);
        lsum[qm][j] += rs[qm][j];
      }
#pragma unroll
    for (int qm = 0; qm < 2; ++qm)
#pragma unroll
      for (int dn = 0; dn < 4; ++dn)
#pragma unroll
        for (int j = 0; j < 4; ++j) acc[qm][dn][j] *= corr[qm][j];

    // P (C-layout) -> LDS -> A-layout frags
#pragma unroll
    for (int qm = 0; qm < 2; ++qm)
#pragma unroll
      for (int kn = 0; kn < 4; ++kn)
#pragma unroll
        for (int j = 0; j < 4; ++j)
          Ps[wave * 2048 + (qm * 16 + lq * 4 + j) * 64 + kn * 16 + lr] = (h16)s[qm][kn][j];

    // O += P @ V
#pragma unroll
    for (int ks = 0; ks < 2; ++ks) {
      h16x8 ap[2], bv4[4];
#pragma unroll
      for (int qm = 0; qm < 2; ++qm)
        ap[qm] = *(const h16x8*)(Ps + wave * 2048 + (qm * 16 + lr) * 64 + ks * 32 + lq * 8);
#pragma unroll
      for (int dn = 0; dn < 4; ++dn)
        bv4[dn] = *(const h16x8*)(Vts + (dn * 16 + lr) * 64 + ks * 32 + lq * 8);
#pragma unroll
      for (int qm = 0; qm < 2; ++qm)
#pragma unroll
        for (int dn = 0; dn < 4; ++dn)
          acc[qm][dn] = __builtin_amdgcn_mfma_f32_16x16x32_f16(ap[qm], bv4[dn], acc[qm][dn], 0, 0, 0);
    }
    __syncthreads();
  }

  // normalize + write O as [B,N,D] f16 (concat heads)
  float rinv[2][4];
#pragma unroll
  for (int qm = 0; qm < 2; ++qm)
#pragma unroll
    for (int j = 0; j < 4; ++j) rinv[qm][j] = 1.0f / lsum[qm][j];
#pragma unroll
  for (int qm = 0; qm < 2; ++qm)
#pragma unroll
    for (int dn = 0; dn < 4; ++dn)
#pragma unroll
      for (int j = 0; j < 4; ++j) {
        const int q = q0 + wave * 32 + qm * 16 + lq * 4 + j;
        const int dk = dn * 16 + lr;
        Oh[((long)b * NN + q) * DD + h * DKK + dk] = (h16)(acc[qm][dn][j] * rinv[qm][j]);
      }
}

// ---------------- launch ----------------
extern "C" void kernel_launch(void* const* d_in, const int* in_sizes, int n_in,
                              void* d_out, int out_size, void* d_ws, size_t ws_size,
                              hipStream_t stream)
{
  const float* H   = (const float*)d_in[0];
  const float* spm = (const float*)d_in[1];
  const float* Wq  = (const float*)d_in[2];
  const float* bq  = (const float*)d_in[3];
  const float* Wk  = (const float*)d_in[4];
  const float* bk  = (const float*)d_in[5];
  const float* Wv  = (const float*)d_in[6];
  const float* bv  = (const float*)d_in[7];
  const float* Wo  = (const float*)d_in[8];
  const float* bo  = (const float*)d_in[9];
  const float* W1  = (const float*)d_in[10];
  const float* b1  = (const float*)d_in[11];
  const float* W2  = (const float*)d_in[12];
  const float* b2  = (const float*)d_in[13];
  float* out = (float*)d_out;

  char* p = (char*)d_ws;
  auto alloc = [&](size_t bytes) { char* r = p; p += (bytes + 255) & ~(size_t)255; return r; };
  h16* ln1   = (h16*)alloc((size_t)MM * DD * 2);        // 16 MB (reused as ln2)
  h16* wqkv  = (h16*)alloc((size_t)3 * DD * DD * 2);    //  6 MB
  h16* wo_t  = (h16*)alloc((size_t)DD * DD * 2);        //  2 MB
  h16* w1_t  = (h16*)alloc((size_t)DD * DFF * 2);       //  8 MB
  h16* w2_t  = (h16*)alloc((size_t)DFF * DD * 2);       //  8 MB
  h16* Qh    = (h16*)alloc((size_t)MM * DD * 2);        // 16 MB (contig 64MB Qh..Oh)
  h16* Kh    = (h16*)alloc((size_t)MM * DD * 2);        // 16 MB
  h16* Vt    = (h16*)alloc((size_t)MM * DD * 2);        // 16 MB (reused as hff)
  h16* Oh    = (h16*)alloc((size_t)MM * DD * 2);        // 16 MB
  float* x   = (float*)alloc((size_t)MM * DD * 4);      // 32 MB
  h16* ln2 = ln1;                                       // alias (ln1 dead after QKV+VT GEMMs)
  h16* hff = Qh;                                        // alias (Q/K/V/O dead after Wo GEMM)

  // 1) LN1
  ln_k<<<MM, 256, 0, stream>>>(H, ln1);
  // 2) weight transpose-casts to f16 B^T layouts
  tcast_k<<<dim3(2, 32, 16),  256, 0, stream>>>(Wq, wqkv,                 DD, DKK, (long)DD * DKK, (long)DKK * DD);
  tcast_k<<<dim3(2, 32, 16),  256, 0, stream>>>(Wk, wqkv + DD * DD,       DD, DKK, (long)DD * DKK, (long)DKK * DD);
  tcast_k<<<dim3(2, 32, 16),  256, 0, stream>>>(Wv, wqkv + 2 * DD * DD,   DD, DKK, (long)DD * DKK, (long)DKK * DD);
  tcast_k<<<dim3(32, 32, 1),  256, 0, stream>>>(Wo, wo_t, DD,  DD,  0, 0);
  tcast_k<<<dim3(128, 32, 1), 256, 0, stream>>>(W1, w1_t, DD,  DFF, 0, 0);
  tcast_k<<<dim3(32, 128, 1), 256, 0, stream>>>(W2, w2_t, DFF, DD,  0, 0);
  // 3a) QK projection (scatters Q,K [b,h,n,dk])
  gemm_k<0><<<dim3(16, 64), 256, 0, stream>>>(ln1, wqkv, DD, 2 * DD, bq, bk, Qh, Kh, nullptr, nullptr);
  // 3b) V^T projection: A = Wv^T-part [dk-rows=1024][d], Bt = ln1 -> Vt [b,h,dk,n] coalesced
  gemm_k<4><<<dim3(64, 8), 256, 0, stream>>>(wqkv + 2 * DD * DD, ln1, DD, MM, bv, nullptr, Vt, nullptr, nullptr, nullptr);
  // 4) attention
  attn_k<<<dim3(4, NHH, BB), 256, 0, stream>>>(Qh, Kh, Vt, spm, Oh);
  // 5) Wo GEMM + residual -> x (fp32)
  gemm_k<1><<<dim3(8, 64), 256, 0, stream>>>(Oh, wo_t, DD, DD, bo, nullptr, nullptr, nullptr, x, H);
  // 6) LN2
  ln_k<<<MM, 256, 0, stream>>>(x, ln2);
  // 7) FFN1 + ReLU -> hff (f16)
  gemm_k<2><<<dim3(32, 64), 256, 0, stream>>>(ln2, w1_t, DD, DFF, b1, nullptr, hff, nullptr, nullptr, nullptr);
  // 8) FFN2 + residual -> out (fp32)
  gemm_k<3><<<dim3(8, 64), 256, 0, stream>>>(hff, w2_t, DFF, DD, b2, nullptr, nullptr, nullptr, out, x);
}

// Round 6
// 519.864 us; speedup vs baseline: 1.2235x; 1.0552x over previous
//
#include <hip/hip_runtime.h>

// ---------------- problem constants ----------------
#define BB   16
#define NN   512
#define DD   1024
#define NHH  16
#define DKK  64
#define DFF  4096
#define MM   (BB*NN)     // 8192 rows

typedef _Float16 h16;
typedef h16  h16x8 __attribute__((ext_vector_type(8)));
typedef h16  h16x4 __attribute__((ext_vector_type(4)));
typedef float f32x4 __attribute__((ext_vector_type(4)));

#define AS1 __attribute__((address_space(1)))
#define AS3 __attribute__((address_space(3)))

__device__ __forceinline__ void gld16(h16* lds_dst, const h16* g_src) {
  // async global->LDS, 16B per lane; LDS dest must be lane-linear (wave-uniform base + lane*16)
  __builtin_amdgcn_global_load_lds((const AS1 void*)g_src, (AS3 void*)lds_dst, 16, 0, 0);
}

// ---------------- LayerNorm row kernel: fp32 [rows][1024] -> f16 ----------------
__global__ __launch_bounds__(256) void ln_k(const float* __restrict__ in, h16* __restrict__ out)
{
  const int row = blockIdx.x;
  const int tid = threadIdx.x;
  const float4 v = ((const float4*)(in + (long)row * DD))[tid];
  float s  = v.x + v.y + v.z + v.w;
  float ss = v.x*v.x + v.y*v.y + v.z*v.z + v.w*v.w;
#pragma unroll
  for (int d = 32; d > 0; d >>= 1) { s += __shfl_down(s, d); ss += __shfl_down(ss, d); }
  __shared__ float red[8];
  const int wv = tid >> 6, ln = tid & 63;
  if (ln == 0) { red[wv] = s; red[4 + wv] = ss; }
  __syncthreads();
  s  = red[0] + red[1] + red[2] + red[3];
  ss = red[4] + red[5] + red[6] + red[7];
  const float mean = s * (1.0f / DD);
  const float var  = ss * (1.0f / DD) - mean * mean;
  const float rstd = rsqrtf(var + 1e-5f);
  h16x4 o;
  o[0] = (h16)((v.x - mean) * rstd);
  o[1] = (h16)((v.y - mean) * rstd);
  o[2] = (h16)((v.z - mean) * rstd);
  o[3] = (h16)((v.w - mean) * rstd);
  ((h16x4*)(out + (long)row * DD))[tid] = o;
}

// ---------------- transpose-cast: src fp32 [R][C] -> dst f16 [C][R], batched ----------------
__global__ __launch_bounds__(256) void tcast_k(const float* __restrict__ src, h16* __restrict__ dst,
                                               int R, int C, long sB, long dB)
{
  __shared__ float tile[32][33];
  const float* s = src + (long)blockIdx.z * sB;
  h16* d = dst + (long)blockIdx.z * dB;
  const int c0 = blockIdx.x * 32, r0 = blockIdx.y * 32;
  const int tx = threadIdx.x & 31, ty = threadIdx.x >> 5;   // 32 x 8
#pragma unroll
  for (int i = 0; i < 32; i += 8)
    tile[ty + i][tx] = s[(long)(r0 + ty + i) * C + c0 + tx];
  __syncthreads();
#pragma unroll
  for (int i = 0; i < 32; i += 8)
    d[(long)(c0 + ty + i) * R + r0 + tx] = (h16)tile[tx][ty + i];
}

// ---------------- f16 MFMA GEMM: C[M][Nc] = A[M][K] * Bt[Nc][K]^T ----------------
// depth-2 pipelined K-loop (3 LDS bufs, counted vmcnt), XOR-swizzled LDS,
// XCD-banded block remap (each XCD owns an m-band, sweeps n fastest).
// EPI 0: QK scatter (+bias)  EPI 1: x = C+bo+H  EPI 2: hff = relu(C+b1)
// EPI 3: out = C+b2+x        EPI 4: Vt scatter (row=dk-index, col=token; bias over row)
template<int EPI>
__global__ __launch_bounds__(256) void gemm_k(
    const h16* __restrict__ A, const h16* __restrict__ Bt, int K, int Nc,
    const float* __restrict__ bias0, const float* __restrict__ bias1,
    h16* __restrict__ o0, h16* __restrict__ o1,
    float* __restrict__ of, const float* __restrict__ addsrc)
{
  __shared__ h16 Asb[3 * 4096];   // 3 bufs x 128x32 f16 = 24 KB
  __shared__ h16 Bsb[3 * 4096];   // 24 KB
  const int tid  = threadIdx.x;
  const int wave = tid >> 6, lane = tid & 63;
  const int lr = lane & 15, lq = lane >> 4;

  // XCD-banded remap: orig%8 ~ XCD (round-robin dispatch); band of Ny/8 m-panels
  // per XCD, n fastest within the band. Bijective (Ny % 8 == 0 for all launches).
  const int nxw = gridDim.x, nyw = gridDim.y;
  const int orig = blockIdx.x + nxw * blockIdx.y;
  const int xcd = orig & 7, sseq = orig >> 3;
  const int by = xcd * (nyw >> 3) + sseq / nxw;
  const int bx = sseq % nxw;
  const int m0 = by * 128, n0 = bx * 128;
  const int wr = (wave >> 1) * 64, wc = (wave & 1) * 64;

  // staging: chunk c (16B) -> LDS linear c*16; global slot XOR-swizzled
  // swizzle (involution): chunk' = chunk ^ ((chunk>>3)&3)  [byte bits 5:4 ^= row bits 2:1]
  const int c0 = tid,       r0 = c0 >> 2, s0 = ((c0 & 3) ^ ((c0 >> 3) & 3)) * 8;
  const int c1 = tid + 256, r1 = c1 >> 2, s1 = ((c1 & 3) ^ ((c1 >> 3) & 3)) * 8;

  // fragment read offsets (h16 elems): row*32 + (lq ^ ((row>>1)&3))*8
  int offA[4], offB[4];
#pragma unroll
  for (int i = 0; i < 4; ++i) {
    const int ra = wr + i * 16 + lr;
    const int rb = wc + i * 16 + lr;
    offA[i] = ra * 32 + (lq ^ ((ra >> 1) & 3)) * 8;
    offB[i] = rb * 32 + (lq ^ ((rb >> 1) & 3)) * 8;
  }

  f32x4 acc[4][4] = {};

  auto STAGE = [&](int k0, int bi) {
    h16* Ad = Asb + bi * 4096;
    h16* Bd = Bsb + bi * 4096;
    gld16(Ad + c0 * 8, A  + (long)(m0 + r0) * K + k0 + s0);
    gld16(Ad + c1 * 8, A  + (long)(m0 + r1) * K + k0 + s1);
    gld16(Bd + c0 * 8, Bt + (long)(n0 + r0) * K + k0 + s0);
    gld16(Bd + c1 * 8, Bt + (long)(n0 + r1) * K + k0 + s1);
  };

  const int nt = K >> 5;           // K/32 tiles (>=32 here)
  STAGE(0, 0);
  STAGE(32, 1);
  int cur = 0, nxt = 2;

  for (int t = 0; t < nt; ++t) {
    if (t + 2 < nt) {
      STAGE((t + 2) << 5, nxt);
      nxt = (nxt == 2) ? 0 : nxt + 1;
    }
    // per-wave wait for tile t's 4 loads (newer prefetches stay in flight)
    if (t + 2 < nt)      asm volatile("s_waitcnt vmcnt(8)" ::: "memory");
    else if (t + 1 < nt) asm volatile("s_waitcnt vmcnt(4)" ::: "memory");
    else                 asm volatile("s_waitcnt vmcnt(0)" ::: "memory");
    __builtin_amdgcn_sched_barrier(0);
    __builtin_amdgcn_s_barrier();            // publish: all waves' tile-t loads landed
    asm volatile("" ::: "memory");

    const h16* Ac = Asb + cur * 4096;
    const h16* Bc = Bsb + cur * 4096;
    h16x8 af[4], bf[4];
#pragma unroll
    for (int i = 0; i < 4; ++i) {
      af[i] = *(const h16x8*)(Ac + offA[i]);
      bf[i] = *(const h16x8*)(Bc + offB[i]);
    }
    // no explicit lgkm fence here: compiler emits fine-grained lgkmcnt so the
    // first MFMAs overlap the tail ds_reads (m97 behavior).
    __builtin_amdgcn_s_setprio(1);
#pragma unroll
    for (int i = 0; i < 4; ++i)
#pragma unroll
      for (int j = 0; j < 4; ++j)
        acc[i][j] = __builtin_amdgcn_mfma_f32_16x16x32_f16(af[i], bf[j], acc[i][j], 0, 0, 0);
    __builtin_amdgcn_s_setprio(0);

    // free the buffer: LDS reads are long complete (MFMAs consumed them), so
    // this lgkmcnt is non-blocking; raw s_barrier avoids __syncthreads' vmcnt(0) drain.
    asm volatile("s_waitcnt lgkmcnt(0)" ::: "memory");
    __builtin_amdgcn_sched_barrier(0);
    __builtin_amdgcn_s_barrier();
    asm volatile("" ::: "memory");

    cur = (cur == 2) ? 0 : cur + 1;
  }

  // epilogue: C/D layout row = (lane>>4)*4 + reg, col = lane&15
#pragma unroll
  for (int i = 0; i < 4; ++i) {
#pragma unroll
    for (int jn = 0; jn < 4; ++jn) {
#pragma unroll
      for (int j = 0; j < 4; ++j) {
        const int m   = m0 + wr + i * 16 + lq * 4 + j;
        const int col = n0 + wc + jn * 16 + lr;
        float v = acc[i][jn][j];
        if constexpr (EPI == 0) {
          const int w  = col >> 10;            // 0=Q 1=K (block-uniform)
          const int hh = (col >> 6) & 15, kk = col & 63;
          const int bidx = m >> 9, nq = m & 511;
          const int bcol = col & 1023;
          if (w == 0) o0[(((long)bidx * NHH + hh) * NN + nq) * DKK + kk] = (h16)(v + bias0[bcol]);
          else        o1[(((long)bidx * NHH + hh) * NN + nq) * DKK + kk] = (h16)(v + bias1[bcol]);
        } else if constexpr (EPI == 1) {
          of[(long)m * Nc + col] = v + bias0[col] + addsrc[(long)m * Nc + col];
        } else if constexpr (EPI == 2) {
          o0[(long)m * Nc + col] = (h16)fmaxf(v + bias0[col], 0.0f);
        } else if constexpr (EPI == 3) {
          of[(long)m * Nc + col] = v + bias0[col] + addsrc[(long)m * Nc + col];
        } else {
          // EPI 4: m = h*64+kk (dk-row), col = token; coalesced over col
          const int bidx = col >> 9, nq = col & 511;
          o0[(((long)bidx * NHH + (m >> 6)) * DKK + (m & 63)) * NN + nq] = (h16)(v + bias0[m]);
        }
      }
    }
  }
}

// ---------------- flash attention: per (b,h), 128 q-rows/block, 64-key chunks ----------------
// All LDS tiles XOR-swizzled: slot' = slot ^ (row&7)  (slot = 16B chunk within 128B row).
// K/V ping-pong double-buffered with counted vmcnt + raw barriers.
__global__ __launch_bounds__(256) void attn_k(
    const h16* __restrict__ Qh, const h16* __restrict__ Kh, const h16* __restrict__ Vt,
    const float* __restrict__ spm, h16* __restrict__ Oh)
{
  __shared__ h16 Qs[128 * 64];      // 16 KB
  __shared__ h16 Ks[2][64 * 64];    // 16 KB  [key][dk] ping-pong
  __shared__ h16 Vts[2][64 * 64];   // 16 KB  [dk][key] ping-pong
  __shared__ h16 Ps[4 * 32 * 64];   // 16 KB  per-wave P
  const int tid  = threadIdx.x;
  const int wave = tid >> 6, lane = tid & 63;
  const int lr = lane & 15, lq = lane >> 4;
  const int b = blockIdx.z, h = blockIdx.y;
  const int q0 = blockIdx.x * 128;
  const long bh = (long)b * NHH + h;
  const h16* Qg = Qh + bh * NN * DKK;
  const h16* Kg = Kh + bh * NN * DKK;
  const h16* Vg = Vt + bh * DKK * NN;

#pragma unroll
  for (int r = 0; r < 4; ++r) {               // stage 128x64 Q once (swizzled source)
    const int c = r * 256 + tid;
    const int row = c >> 3, sl = c & 7;
    gld16(Qs + c * 8, Qg + (long)(q0 + row) * DKK + ((sl ^ (row & 7)) * 8));
  }

  auto STAGEKV = [&](int kc, int bi) {
#pragma unroll
    for (int r = 0; r < 2; ++r) {
      const int c = r * 256 + tid;
      const int row = c >> 3, sl = c & 7;
      const int sg = (sl ^ (row & 7)) * 8;
      gld16(&Ks[bi][c * 8],  Kg + (long)(kc + row) * DKK + sg);
      gld16(&Vts[bi][c * 8], Vg + (long)row * NN + kc + sg);
    }
  };
  STAGEKV(0, 0);

  f32x4 acc[2][4] = {};
  float mrow[2][4], lsum[2][4];
#pragma unroll
  for (int a = 0; a < 2; ++a)
#pragma unroll
    for (int j = 0; j < 4; ++j) { mrow[a][j] = -3.0e38f; lsum[a][j] = 0.0f; }

  const int NT = NN / 64;   // 8 chunks
  for (int t = 0; t < NT; ++t) {
    const int kc = t * 64;
    if (t + 1 < NT) {
      STAGEKV(kc + 64, (t + 1) & 1);
      asm volatile("s_waitcnt vmcnt(4)" ::: "memory");   // tile-t (and Q) landed
    } else {
      asm volatile("s_waitcnt vmcnt(0)" ::: "memory");
    }
    __builtin_amdgcn_sched_barrier(0);
    __builtin_amdgcn_s_barrier();
    asm volatile("" ::: "memory");

    const h16* Kc = Ks[t & 1];
    const h16* Vc = Vts[t & 1];

    // S = Q K^T  (2 qm-frags x 4 kn-frags, DK=64 -> 2 mfma steps); swizzled reads
    f32x4 s[2][4] = {};
#pragma unroll
    for (int ks = 0; ks < 2; ++ks) {
      h16x8 aq[2], bk4[4];
#pragma unroll
      for (int qm = 0; qm < 2; ++qm) {
        const int row = wave * 32 + qm * 16 + lr;
        aq[qm] = *(const h16x8*)(Qs + row * 64 + ((ks * 4 + lq) ^ (row & 7)) * 8);
      }
#pragma unroll
      for (int kn = 0; kn < 4; ++kn) {
        const int row = kn * 16 + lr;
        bk4[kn] = *(const h16x8*)(Kc + row * 64 + ((ks * 4 + lq) ^ (row & 7)) * 8);
      }
      __builtin_amdgcn_s_setprio(1);
#pragma unroll
      for (int qm = 0; qm < 2; ++qm)
#pragma unroll
        for (int kn = 0; kn < 4; ++kn)
          s[qm][kn] = __builtin_amdgcn_mfma_f32_16x16x32_f16(aq[qm], bk4[kn], s[qm][kn], 0, 0, 0);
      __builtin_amdgcn_s_setprio(0);
    }

    // scale + spm bias, row-max
    float pm[2][4];
#pragma unroll
    for (int qm = 0; qm < 2; ++qm)
#pragma unroll
      for (int j = 0; j < 4; ++j) pm[qm][j] = -3.0e38f;
#pragma unroll
    for (int qm = 0; qm < 2; ++qm)
#pragma unroll
      for (int kn = 0; kn < 4; ++kn)
#pragma unroll
        for (int j = 0; j < 4; ++j) {
          const int q = q0 + wave * 32 + qm * 16 + lq * 4 + j;
          const int key = kc + kn * 16 + lr;
          float v = s[qm][kn][j] * 0.125f + spm[((long)b * NN + q) * NN + key];
          s[qm][kn][j] = v;
          pm[qm][j] = fmaxf(pm[qm][j], v);
        }
#pragma unroll
    for (int qm = 0; qm < 2; ++qm)
#pragma unroll
      for (int j = 0; j < 4; ++j) {
#pragma unroll
        for (int d = 1; d < 16; d <<= 1) pm[qm][j] = fmaxf(pm[qm][j], __shfl_xor(pm[qm][j], d));
      }
    // online-softmax update
    float corr[2][4];
#pragma unroll
    for (int qm = 0; qm < 2; ++qm)
#pragma unroll
      for (int j = 0; j < 4; ++j) {
        const float mn = fmaxf(mrow[qm][j], pm[qm][j]);
        corr[qm][j] = __expf(mrow[qm][j] - mn);
        mrow[qm][j] = mn;
        lsum[qm][j] *= corr[qm][j];
      }
    float rs[2][4] = {};
#pragma unroll
    for (int qm = 0; qm < 2; ++qm)
#pragma unroll
      for (int kn = 0; kn < 4; ++kn)
#pragma unroll
        for (int j = 0; j < 4; ++j) {
          const float pexp = __expf(s[qm][kn][j] - mrow[qm][j]);
          s[qm][kn][j] = pexp;
          rs[qm][j] += pexp;
        }
#pragma unroll
    for (int qm = 0; qm < 2; ++qm)
#pragma unroll
      for (int j = 0; j < 4; ++j) {
#pragma unroll
        for (int d = 1; d < 16; d <<= 1) rs[qm][j] += __shfl_xor(rs[qm][j], d);
        lsum[qm][j] += rs[qm][j];
      }
#pragma unroll
    for (int qm = 0; qm < 2; ++qm)
#pragma unroll
      for (int dn = 0; dn < 4; ++dn)
#pragma unroll
        for (int j = 0; j < 4; ++j) acc[qm][dn][j] *= corr[qm][j];

    // P (C-layout) -> LDS (swizzled) -> A-layout frags
#pragma unroll
    for (int qm = 0; qm < 2; ++qm)
#pragma unroll
      for (int kn = 0; kn < 4; ++kn)
#pragma unroll
        for (int j = 0; j < 4; ++j) {
          const int row = qm * 16 + lq * 4 + j;
          const int sl  = (kn * 2 + (lr >> 3)) ^ (row & 7);
          Ps[wave * 2048 + row * 64 + sl * 8 + (lr & 7)] = (h16)s[qm][kn][j];
        }

    // O += P @ V  (swizzled reads)
#pragma unroll
    for (int ks = 0; ks < 2; ++ks) {
      h16x8 ap[2], bv4[4];
#pragma unroll
      for (int qm = 0; qm < 2; ++qm) {
        const int row = qm * 16 + lr;
        ap[qm] = *(const h16x8*)(Ps + wave * 2048 + row * 64 + ((ks * 4 + lq) ^ (row & 7)) * 8);
      }
#pragma unroll
      for (int dn = 0; dn < 4; ++dn) {
        const int row = dn * 16 + lr;
        bv4[dn] = *(const h16x8*)(Vc + row * 64 + ((ks * 4 + lq) ^ (row & 7)) * 8);
      }
      __builtin_amdgcn_s_setprio(1);
#pragma unroll
      for (int qm = 0; qm < 2; ++qm)
#pragma unroll
        for (int dn = 0; dn < 4; ++dn)
          acc[qm][dn] = __builtin_amdgcn_mfma_f32_16x16x32_f16(ap[qm], bv4[dn], acc[qm][dn], 0, 0, 0);
      __builtin_amdgcn_s_setprio(0);
    }

    // all LDS reads of this chunk's K/V done -> next stage may overwrite
    asm volatile("s_waitcnt lgkmcnt(0)" ::: "memory");
    __builtin_amdgcn_sched_barrier(0);
    __builtin_amdgcn_s_barrier();
    asm volatile("" ::: "memory");
  }

  // normalize + write O as [B,N,D] f16 (concat heads)
  float rinv[2][4];
#pragma unroll
  for (int qm = 0; qm < 2; ++qm)
#pragma unroll
    for (int j = 0; j < 4; ++j) rinv[qm][j] = 1.0f / lsum[qm][j];
#pragma unroll
  for (int qm = 0; qm < 2; ++qm)
#pragma unroll
    for (int dn = 0; dn < 4; ++dn)
#pragma unroll
      for (int j = 0; j < 4; ++j) {
        const int q = q0 + wave * 32 + qm * 16 + lq * 4 + j;
        const int dk = dn * 16 + lr;
        Oh[((long)b * NN + q) * DD + h * DKK + dk] = (h16)(acc[qm][dn][j] * rinv[qm][j]);
      }
}

// ---------------- launch ----------------
extern "C" void kernel_launch(void* const* d_in, const int* in_sizes, int n_in,
                              void* d_out, int out_size, void* d_ws, size_t ws_size,
                              hipStream_t stream)
{
  const float* H   = (const float*)d_in[0];
  const float* spm = (const float*)d_in[1];
  const float* Wq  = (const float*)d_in[2];
  const float* bq  = (const float*)d_in[3];
  const float* Wk  = (const float*)d_in[4];
  const float* bk  = (const float*)d_in[5];
  const float* Wv  = (const float*)d_in[6];
  const float* bv  = (const float*)d_in[7];
  const float* Wo  = (const float*)d_in[8];
  const float* bo  = (const float*)d_in[9];
  const float* W1  = (const float*)d_in[10];
  const float* b1  = (const float*)d_in[11];
  const float* W2  = (const float*)d_in[12];
  const float* b2  = (const float*)d_in[13];
  float* out = (float*)d_out;

  char* p = (char*)d_ws;
  auto alloc = [&](size_t bytes) { char* r = p; p += (bytes + 255) & ~(size_t)255; return r; };
  h16* ln1   = (h16*)alloc((size_t)MM * DD * 2);        // 16 MB (reused as ln2)
  h16* wqkv  = (h16*)alloc((size_t)3 * DD * DD * 2);    //  6 MB
  h16* wo_t  = (h16*)alloc((size_t)DD * DD * 2);        //  2 MB
  h16* w1_t  = (h16*)alloc((size_t)DD * DFF * 2);       //  8 MB
  h16* w2_t  = (h16*)alloc((size_t)DFF * DD * 2);       //  8 MB
  h16* Qh    = (h16*)alloc((size_t)MM * DD * 2);        // 16 MB (contig 64MB Qh..Oh)
  h16* Kh    = (h16*)alloc((size_t)MM * DD * 2);        // 16 MB
  h16* Vt    = (h16*)alloc((size_t)MM * DD * 2);        // 16 MB (reused as hff)
  h16* Oh    = (h16*)alloc((size_t)MM * DD * 2);        // 16 MB
  float* x   = (float*)alloc((size_t)MM * DD * 4);      // 32 MB
  h16* ln2 = ln1;                                       // alias (ln1 dead after QKV+VT GEMMs)
  h16* hff = Qh;                                        // alias (Q/K/V/O dead after Wo GEMM)

  // 1) LN1
  ln_k<<<MM, 256, 0, stream>>>(H, ln1);
  // 2) weight transpose-casts to f16 B^T layouts
  tcast_k<<<dim3(2, 32, 16),  256, 0, stream>>>(Wq, wqkv,                 DD, DKK, (long)DD * DKK, (long)DKK * DD);
  tcast_k<<<dim3(2, 32, 16),  256, 0, stream>>>(Wk, wqkv + DD * DD,       DD, DKK, (long)DD * DKK, (long)DKK * DD);
  tcast_k<<<dim3(2, 32, 16),  256, 0, stream>>>(Wv, wqkv + 2 * DD * DD,   DD, DKK, (long)DD * DKK, (long)DKK * DD);
  tcast_k<<<dim3(32, 32, 1),  256, 0, stream>>>(Wo, wo_t, DD,  DD,  0, 0);
  tcast_k<<<dim3(128, 32, 1), 256, 0, stream>>>(W1, w1_t, DD,  DFF, 0, 0);
  tcast_k<<<dim3(32, 128, 1), 256, 0, stream>>>(W2, w2_t, DFF, DD,  0, 0);
  // 3a) QK projection (scatters Q,K [b,h,n,dk])
  gemm_k<0><<<dim3(16, 64), 256, 0, stream>>>(ln1, wqkv, DD, 2 * DD, bq, bk, Qh, Kh, nullptr, nullptr);
  // 3b) V^T projection: A = Wv^T-part [dk-rows=1024][d], Bt = ln1 -> Vt [b,h,dk,n] coalesced
  gemm_k<4><<<dim3(64, 8), 256, 0, stream>>>(wqkv + 2 * DD * DD, ln1, DD, MM, bv, nullptr, Vt, nullptr, nullptr, nullptr);
  // 4) attention
  attn_k<<<dim3(4, NHH, BB), 256, 0, stream>>>(Qh, Kh, Vt, spm, Oh);
  // 5) Wo GEMM + residual -> x (fp32)
  gemm_k<1><<<dim3(8, 64), 256, 0, stream>>>(Oh, wo_t, DD, DD, bo, nullptr, nullptr, nullptr, x, H);
  // 6) LN2
  ln_k<<<MM, 256, 0, stream>>>(x, ln2);
  // 7) FFN1 + ReLU -> hff (f16)
  gemm_k<2><<<dim3(32, 64), 256, 0, stream>>>(ln2, w1_t, DD, DFF, b1, nullptr, hff, nullptr, nullptr, nullptr);
  // 8) FFN2 + residual -> out (fp32)
  gemm_k<3><<<dim3(8, 64), 256, 0, stream>>>(hff, w2_t, DFF, DD, b2, nullptr, nullptr, nullptr, out, x);
}